// Round 11
// baseline (199.730 us; speedup 1.0000x reference)
//
#include <hip/hip_runtime.h>

#define NN 50000
#define NE 800000
#define NG 64
#define NB ((NN + 255) / 256)   // 196 scan blocks
#define WSTR 164   // per-o weight column stride (floats): 160 used + pad, 16B-aligned

// ---------------------------------------------------------------------------
// deg histogram (int)
// ---------------------------------------------------------------------------
__global__ __launch_bounds__(256) void histk(const int* __restrict__ dst,
                                             int* __restrict__ deg) {
    int e = blockIdx.x * 256 + threadIdx.x;
    if (e < NE) atomicAdd(&deg[dst[e]], 1);
}

// ---------------------------------------------------------------------------
// decoupled scan, stage 1: per-block (256-elem) sums of deg
// ---------------------------------------------------------------------------
__global__ __launch_bounds__(256) void bsumk(const int* __restrict__ deg,
                                             int* __restrict__ bsum) {
    int idx = blockIdx.x * 256 + threadIdx.x;
    int v = (idx < NN) ? deg[idx] : 0;
#pragma unroll
    for (int off = 32; off > 0; off >>= 1) v += __shfl_down(v, off);
    __shared__ int ws[4];
    int lane = threadIdx.x & 63, w = threadIdx.x >> 6;
    if (lane == 0) ws[w] = v;
    __syncthreads();
    if (threadIdx.x == 0) bsum[blockIdx.x] = ws[0] + ws[1] + ws[2] + ws[3];
}

// ---------------------------------------------------------------------------
// stage 2: exclusive scan of the NB block sums (single tiny block)
// ---------------------------------------------------------------------------
__global__ __launch_bounds__(256) void bscank(const int* __restrict__ bsum,
                                              int* __restrict__ boffs) {
    int tid = threadIdx.x;
    int v = (tid < NB) ? bsum[tid] : 0;
    int lane = tid & 63, w = tid >> 6;
    int t = v;
#pragma unroll
    for (int off = 1; off < 64; off <<= 1) {
        int u = __shfl_up(t, off);
        if (lane >= off) t += u;
    }
    __shared__ int ws[4];
    if (lane == 63) ws[w] = t;
    __syncthreads();
    int add = 0;
    for (int k = 0; k < w; k++) add += ws[k];
    if (tid < NB) boffs[tid] = add + t - v;   // exclusive prefix
}

// ---------------------------------------------------------------------------
// stage 3: in-block exclusive scan + block offset -> row[NN+1], cur[NN]
// ---------------------------------------------------------------------------
__global__ __launch_bounds__(256) void fscank(const int* __restrict__ deg,
                                              const int* __restrict__ boffs,
                                              int* __restrict__ row,
                                              int* __restrict__ cur) {
    int idx = blockIdx.x * 256 + threadIdx.x;
    int v = (idx < NN) ? deg[idx] : 0;
    int lane = threadIdx.x & 63, w = threadIdx.x >> 6;
    int t = v;
#pragma unroll
    for (int off = 1; off < 64; off <<= 1) {
        int u = __shfl_up(t, off);
        if (lane >= off) t += u;
    }
    __shared__ int ws[4];
    if (lane == 63) ws[w] = t;
    __syncthreads();
    int add = boffs[blockIdx.x];
    for (int k = 0; k < w; k++) add += ws[k];
    int ex = add + t - v;
    if (idx < NN) { row[idx] = ex; cur[idx] = ex; }
    else if (idx == NN) row[NN] = ex;   // == NE
}

// ---------------------------------------------------------------------------
// cooperative scatter: 4 lanes per edge record. ea read is coalesced float2
// per lane; 6-shfl butterfly gives each lane all 8 ea values; leader lane
// does the cur atomic and broadcasts pos; each lane stores one 16B quarter
// -> the 4 stores coalesce into ONE 64B write transaction per record
// (Round-10 scatk: 4 independent 16B stores per record = 4x transactions).
// ---------------------------------------------------------------------------
__global__ __launch_bounds__(256) void scatk(const int* __restrict__ src,
                                             const int* __restrict__ dst,
                                             const float* __restrict__ ea,
                                             int* __restrict__ cur,
                                             float* __restrict__ rec) {
    int tid = threadIdx.x;
    int grp = tid >> 2;               // 64 edge-groups per block
    int j = tid & 3;
    int e = blockIdx.x * 64 + grp;    // NE = 800000 = 12500*64, exact
    // coalesced: lane j reads ea[e*8 + 2j .. 2j+1]
    float2 q = *(const float2*)(ea + (size_t)e * 8 + j * 2);
    float r0 = q.x, r1 = q.y;
    float s0 = __shfl_xor(r0, 1);
    float s1 = __shfl_xor(r1, 1);
    // A..D = ea[4h .. 4h+3], h = j>>1
    float A = (j & 1) ? s0 : r0;
    float B = (j & 1) ? s1 : r1;
    float C = (j & 1) ? r0 : s0;
    float D = (j & 1) ? r1 : s1;
    float e0 = __shfl_xor(A, 2);
    float e1 = __shfl_xor(B, 2);
    float e2 = __shfl_xor(C, 2);
    float e3 = __shfl_xor(D, 2);
    int h = j >> 1;
    float L0 = h ? e0 : A, L1 = h ? e1 : B, L2 = h ? e2 : C, L3 = h ? e3 : D;
    float H0 = h ? A : e0, H1 = h ? B : e1, H2 = h ? C : e2, H3 = h ? D : e3;

    int pos = 0, sv = 0;
    if (j == 0) {
        sv = src[e];
        pos = atomicAdd(&cur[dst[e]], 1);
    }
    pos = __shfl(pos, (tid & 63) & ~3);   // broadcast from group leader

    float4 w;
    if (j == 0)      { w.x = __int_as_float(sv); w.y = L0; w.z = L1; w.w = L2; }
    else if (j == 1) { w.x = L3; w.y = H0; w.z = H1; w.w = H2; }
    else if (j == 2) { w.x = H3; w.y = 0.f; w.z = 0.f; w.w = 0.f; }
    else             { w.x = 0.f; w.y = 0.f; w.z = 0.f; w.w = 0.f; }
    *(float4*)(rec + (size_t)pos * 16 + j * 4) = w;
}

// ---------------------------------------------------------------------------
// fused edge+node layer. Edge loop unrolled x8 (8 independent rec streams +
// 8 independent x-gathers in flight per thread).
// ---------------------------------------------------------------------------
template <bool POOL>
__global__ __launch_bounds__(256) void fusedk(const float* __restrict__ xin,
                                              const int* __restrict__ row,
                                              const float* __restrict__ rec,
                                              const float* __restrict__ we,
                                              const float* __restrict__ be,
                                              const float* __restrict__ root,
                                              const float* __restrict__ bias,
                                              const int* __restrict__ batch,
                                              float* __restrict__ out,
                                              float* __restrict__ gsum,
                                              float* __restrict__ gcnt) {
    __shared__ float wt[16 * WSTR];
    __shared__ float pls[16][WSTR];
    __shared__ float bs[16];
    __shared__ float gacc[16][16];
    __shared__ int gcnta[16];
    int tid = threadIdx.x;
    for (int idx = tid; idx < 2048; idx += 256) {
        int f = idx >> 8; int i = (idx >> 4) & 15; int o = idx & 15;
        wt[o * WSTR + f * 16 + i] = we[idx];
    }
    {
        int i = tid >> 4, o = tid & 15;
        wt[o * WSTR + 128 + i] = be[tid];
        wt[o * WSTR + 144 + i] = root[tid];
    }
    if (tid < 16) bs[tid] = bias[tid];
    if (POOL) {
        gacc[tid >> 4][tid & 15] = 0.f;
        if (tid < 16) gcnta[tid] = 0;
    }

    int g = tid >> 4, t = tid & 15;
    int v = blockIdx.x * 16 + g;
    int r0 = row[v], r1 = row[v + 1];

    float p0 = 0.f, p1 = 0.f, p2 = 0.f, p3 = 0.f;
    float p4 = 0.f, p5 = 0.f, p6 = 0.f, p7 = 0.f, s = 0.f;

    int pos = r0;
    int pend = r0 + ((r1 - r0) & ~7);
    for (; pos < pend; pos += 8) {
        float4 a[8], b[8];
        float e9[8], xs[8];
#pragma unroll
        for (int k = 0; k < 8; k++) {
            const float* q = rec + (size_t)(pos + k) * 16;
            a[k] = *(const float4*)q;
            b[k] = *(const float4*)(q + 4);
            e9[k] = q[8];
        }
#pragma unroll
        for (int k = 0; k < 8; k++)
            xs[k] = xin[(size_t)__float_as_int(a[k].x) * 16 + t];
#pragma unroll
        for (int k = 0; k < 8; k++) {
            float xv = xs[k];
            p0 += a[k].y * xv; p1 += a[k].z * xv; p2 += a[k].w * xv; p3 += b[k].x * xv;
            p4 += b[k].y * xv; p5 += b[k].z * xv; p6 += b[k].w * xv; p7 += e9[k] * xv;
            s += xv;
        }
    }
    for (; pos < r1; ++pos) {
        const float* q = rec + (size_t)pos * 16;
        float4 a = *(const float4*)q; float4 b = *(const float4*)(q + 4); float e8 = q[8];
        float xv = xin[(size_t)__float_as_int(a.x) * 16 + t];
        p0 += a.y * xv; p1 += a.z * xv; p2 += a.w * xv; p3 += b.x * xv;
        p4 += b.y * xv; p5 += b.z * xv; p6 += b.w * xv; p7 += e8 * xv; s += xv;
    }

    pls[g][0 * 16 + t] = p0; pls[g][1 * 16 + t] = p1;
    pls[g][2 * 16 + t] = p2; pls[g][3 * 16 + t] = p3;
    pls[g][4 * 16 + t] = p4; pls[g][5 * 16 + t] = p5;
    pls[g][6 * 16 + t] = p6; pls[g][7 * 16 + t] = p7;
    pls[g][128 + t] = s;
    pls[g][144 + t] = xin[(size_t)v * 16 + t];
    __syncthreads();

    int o = t;
    const float4* pv = (const float4*)pls[g];
    const float4* wc = (const float4*)(wt + o * WSTR);
    float agg = 0.f;
#pragma unroll
    for (int k = 0; k < 36; k++) {        // 144 floats: we (128) + be*S (16)
        float4 a = pv[k]; float4 wv = wc[k];
        agg += a.x * wv.x + a.y * wv.y + a.z * wv.z + a.w * wv.w;
    }
    float r = 0.f;
#pragma unroll
    for (int k = 36; k < 40; k++) {       // root part (16 floats)
        float4 a = pv[k]; float4 wv = wc[k];
        r += a.x * wv.x + a.y * wv.y + a.z * wv.z + a.w * wv.w;
    }
    int dg = r1 - r0;
    float h = r + agg / (float)(dg > 1 ? dg : 1) + bs[o];

    if (!POOL) {
        out[(size_t)v * 16 + o] = h;
    } else {
        int bmin = batch[blockIdx.x * 16];
        int b = batch[v];
        int slot = b - bmin;
        if (slot < 16) {
            atomicAdd(&gacc[slot][o], h);
            if (o == 0) atomicAdd(&gcnta[slot], 1);
        } else {
            atomicAdd(&gsum[(size_t)b * 16 + o], h);
            if (o == 0) atomicAdd(&gcnt[b], 1.0f);
        }
        __syncthreads();
        if (gcnta[g] > 0) {
            atomicAdd(&gsum[(size_t)(bmin + g) * 16 + o], gacc[g][o]);
            if (o == 0) atomicAdd(&gcnt[bmin + g], (float)gcnta[g]);
        }
    }
}

// ---------------------------------------------------------------------------
// final divide over all NG*16 = 1024 outputs
// ---------------------------------------------------------------------------
__global__ void fink(const float* __restrict__ gsum,
                     const float* __restrict__ gcnt,
                     float* __restrict__ out) {
    int i = blockIdx.x * 256 + threadIdx.x;
    if (i < NG * 16) out[i] = gsum[i] / fmaxf(gcnt[i >> 4], 1.0f);
}

extern "C" void kernel_launch(void* const* d_in, const int* in_sizes, int n_in,
                              void* d_out, int out_size, void* d_ws, size_t ws_size,
                              hipStream_t stream) {
    const float* x     = (const float*)d_in[0];
    const int*   ei    = (const int*)d_in[1];
    const float* ea    = (const float*)d_in[2];
    const int*   batch = (const int*)d_in[3];
    const float* we1   = (const float*)d_in[4];
    const float* be1   = (const float*)d_in[5];
    const float* root1 = (const float*)d_in[6];
    const float* bias1 = (const float*)d_in[7];
    const float* we2   = (const float*)d_in[8];
    const float* be2   = (const float*)d_in[9];
    const float* root2 = (const float*)d_in[10];
    const float* bias2 = (const float*)d_in[11];

    float* ws = (float*)d_ws;
    float* rec  = ws;                                   // NE*16 floats, 64B-aligned
    float* h1   = rec + (size_t)NE * 16;                // NN*16
    int*   row  = (int*)(h1 + (size_t)NN * 16);         // NN+1
    int*   cur  = row + NN + 1;                         // NN
    int*   deg  = cur + NN;                             // NN
    int*   bsum = deg + NN;                             // NB
    int*   boffs= bsum + NB;                            // NB
    float* gsum = (float*)(boffs + NB);                 // NG*16
    float* gcnt = gsum + NG * 16;                       // NG

    // zero deg + bsum + boffs + gsum + gcnt (contiguous)
    hipMemsetAsync(deg, 0, (size_t)(NN + 2 * NB + NG * 16 + NG) * 4, stream);

    const int* src = ei;
    const int* dst = ei + NE;

    int gE = (NE + 255) / 256;   // 3125
    int gS = NE / 64;            // 12500 (exact) — 4 lanes per edge
    int gV = NN / 16;            // 3125 (exact)

    histk<<<gE, 256, 0, stream>>>(dst, deg);
    bsumk<<<NB, 256, 0, stream>>>(deg, bsum);
    bscank<<<1, 256, 0, stream>>>(bsum, boffs);
    fscank<<<NB, 256, 0, stream>>>(deg, boffs, row, cur);
    scatk<<<gS, 256, 0, stream>>>(src, dst, ea, cur, rec);

    // layer 1
    fusedk<false><<<gV, 256, 0, stream>>>(x, row, rec, we1, be1, root1, bias1,
                                          batch, h1, gsum, gcnt);
    // layer 2 (+ pooling)
    fusedk<true><<<gV, 256, 0, stream>>>(h1, row, rec, we2, be2, root2, bias2,
                                         batch, h1 /*unused*/, gsum, gcnt);

    fink<<<4, 256, 0, stream>>>(gsum, gcnt, (float*)d_out);
}